// Round 20
// baseline (108.380 us; speedup 1.0000x reference)
//
#include <hip/hip_runtime.h>

namespace {

struct f3 { float x, y, z; };   // size 12, align 4 -> global_load_dwordx3

constexpr int NB = 4, ND = 128, NH = 192, NW = 192;
constexpr int PLI = NH * NW;
constexpr int CD = 16;    // output planes per block; 128/16 = 8 exact

__global__ __launch_bounds__(256, 2)
void edge_loss3d(const float* __restrict__ pred,
                 const float* __restrict__ targ,
                 float* __restrict__ out)
{
    const int lane = threadIdx.x & 63;
    const int wid  = threadIdx.x >> 6;
    const int d0   = blockIdx.x * CD;
    const int h    = blockIdx.y * 12 + 3 * wid; // wave's output rows h..h+2

    // 5 input rows h-1..h+3 (clamped) + wave-uniform edge masks
    const int ro0 = (h - 1 < 0 ? 0 : h - 1) * NW;
    const int ro1 = h * NW;
    const int ro2 = (h + 1) * NW;
    const int ro3 = (h + 2) * NW;                      // always valid
    const int ro4 = (h + 3 > NH - 1 ? NH - 1 : h + 3) * NW;
    const float m0 = (h - 1 >= 0) ? 1.f : 0.f;
    const float m4 = (h + 3 < NH) ? 1.f : 0.f;

    // rolling UNSCALED conv state: q[tensor][slot][kind][row][w]
    float q[2][3][3][3][3];
    float acc = 0.f;

// write one output row's (ss,ts,st) from named u/v + halos (literal indices)
#define QROW(T, SP, R, U0, U1, U2, UM, UP, V0, V1, V2, VM, VP) do {           \
    q[T][SP][0][R][0] = fmaf(2.f, U0, UM + U1);                               \
    q[T][SP][0][R][1] = fmaf(2.f, U1, U0 + U2);                               \
    q[T][SP][0][R][2] = fmaf(2.f, U2, U1 + UP);                               \
    q[T][SP][1][R][0] = fmaf(2.f, V0, VM + V1);                               \
    q[T][SP][1][R][1] = fmaf(2.f, V1, V0 + V2);                               \
    q[T][SP][1][R][2] = fmaf(2.f, V2, V1 + VP);                               \
    q[T][SP][2][R][0] = U1 - UM;                                              \
    q[T][SP][2][R][1] = U2 - U0;                                              \
    q[T][SP][2][R][2] = UP - U1;                                              \
} while (0)

// one tensor, one plane, into slot SP. PM = plane mask (1.f folds away).
// 5 x dwordx3 loads, h-conv for 3 output rows, w-halo via 12 shuffles.
#define TPASS(T, SP, OFS, PM) do {                                            \
    const float* s_ = (T) ? sb1 : sb0;                                        \
    const f3 A_ = *(const f3*)(s_ + (OFS) + ro0);                             \
    const f3 B_ = *(const f3*)(s_ + (OFS) + ro1);                             \
    const f3 C_ = *(const f3*)(s_ + (OFS) + ro2);                             \
    const f3 D_ = *(const f3*)(s_ + (OFS) + ro3);                             \
    const f3 E_ = *(const f3*)(s_ + (OFS) + ro4);                             \
    const float a0_ = A_.x * m0, a1_ = A_.y * m0, a2_ = A_.z * m0;            \
    const float y0_ = E_.x * m4, y1_ = E_.y * m4, y2_ = E_.z * m4;            \
    float uA0_ = fmaf(2.f, B_.x, a0_ + C_.x) * (PM);                          \
    float uA1_ = fmaf(2.f, B_.y, a1_ + C_.y) * (PM);                          \
    float uA2_ = fmaf(2.f, B_.z, a2_ + C_.z) * (PM);                          \
    float uB0_ = fmaf(2.f, C_.x, B_.x + D_.x) * (PM);                         \
    float uB1_ = fmaf(2.f, C_.y, B_.y + D_.y) * (PM);                         \
    float uB2_ = fmaf(2.f, C_.z, B_.z + D_.z) * (PM);                         \
    float uC0_ = fmaf(2.f, D_.x, C_.x + y0_) * (PM);                          \
    float uC1_ = fmaf(2.f, D_.y, C_.y + y1_) * (PM);                          \
    float uC2_ = fmaf(2.f, D_.z, C_.z + y2_) * (PM);                          \
    float vA0_ = (C_.x - a0_) * (PM), vA1_ = (C_.y - a1_) * (PM), vA2_ = (C_.z - a2_) * (PM); \
    float vB0_ = (D_.x - B_.x) * (PM), vB1_ = (D_.y - B_.y) * (PM), vB2_ = (D_.z - B_.z) * (PM); \
    float vC0_ = (y0_ - C_.x) * (PM), vC1_ = (y1_ - C_.y) * (PM), vC2_ = (y2_ - C_.z) * (PM); \
    float uAm_ = __shfl_up(uA2_, 1, 64), uAp_ = __shfl_down(uA0_, 1, 64);     \
    float uBm_ = __shfl_up(uB2_, 1, 64), uBp_ = __shfl_down(uB0_, 1, 64);     \
    float uCm_ = __shfl_up(uC2_, 1, 64), uCp_ = __shfl_down(uC0_, 1, 64);     \
    float vAm_ = __shfl_up(vA2_, 1, 64), vAp_ = __shfl_down(vA0_, 1, 64);     \
    float vBm_ = __shfl_up(vB2_, 1, 64), vBp_ = __shfl_down(vB0_, 1, 64);     \
    float vCm_ = __shfl_up(vC2_, 1, 64), vCp_ = __shfl_down(vC0_, 1, 64);     \
    if (lane == 0)  { uAm_ = 0.f; uBm_ = 0.f; uCm_ = 0.f;                     \
                      vAm_ = 0.f; vBm_ = 0.f; vCm_ = 0.f; }                   \
    if (lane == 63) { uAp_ = 0.f; uBp_ = 0.f; uCp_ = 0.f;                     \
                      vAp_ = 0.f; vBp_ = 0.f; vCp_ = 0.f; }                   \
    QROW(T, SP, 0, uA0_, uA1_, uA2_, uAm_, uAp_, vA0_, vA1_, vA2_, vAm_, vAp_); \
    QROW(T, SP, 1, uB0_, uB1_, uB2_, uBm_, uBp_, vB0_, vB1_, vB2_, vBm_, vBp_); \
    QROW(T, SP, 2, uC0_, uC1_, uC2_, uCm_, uCp_, vC0_, vC1_, vC2_, vCm_, vCp_); \
} while (0)

// both tensors, plane P guaranteed in range
#define TPP(SP, P) do {                                                       \
    const int o_ = (P) * PLI;                                                 \
    TPASS(0, SP, o_, 1.f); TPASS(1, SP, o_, 1.f);                             \
} while (0)

// both tensors, plane P may be out of range (blocks at d-edges)
#define TPM(SP, P) do {                                                       \
    const int pc_ = (P) < 0 ? 0 : ((P) > ND - 1 ? ND - 1 : (P));              \
    const float pm_ = ((P) >= 0 && (P) < ND) ? 1.f : 0.f;                     \
    const int o_ = pc_ * PLI;                                                 \
    TPASS(0, SP, o_, pm_); TPASS(1, SP, o_, pm_);                             \
} while (0)

// unscaled magnitude: conv scales exactly 16x; eps_u = 256e-8; v_sqrt 1 inst
#define EDGE1(T, R, J, SM, SC, SP, E) do {                                    \
    const float gx_ = fmaf(2.f, q[T][SC][2][R][J], q[T][SM][2][R][J] + q[T][SP][2][R][J]); \
    const float gy_ = fmaf(2.f, q[T][SC][1][R][J], q[T][SM][1][R][J] + q[T][SP][1][R][J]); \
    const float gz_ = q[T][SP][0][R][J] - q[T][SM][0][R][J];                  \
    const float d_ = fmaf(gz_, gz_, fmaf(gy_, gy_, fmaf(gx_, gx_, 2.56e-6f)));\
    asm("v_sqrt_f32 %0, %1" : "=v"(E) : "v"(d_));                             \
} while (0)

#define EMIT1(R, J, SM, SC, SP) do {                                          \
    float e0_, e1_;                                                           \
    EDGE1(0, R, J, SM, SC, SP, e0_);                                          \
    EDGE1(1, R, J, SM, SC, SP, e1_);                                          \
    acc += fabsf(e0_ - e1_);                                                  \
} while (0)

#define EMIT(SM, SC, SP) do {                                                 \
    EMIT1(0, 0, SM, SC, SP); EMIT1(0, 1, SM, SC, SP); EMIT1(0, 2, SM, SC, SP);\
    EMIT1(1, 0, SM, SC, SP); EMIT1(1, 1, SM, SC, SP); EMIT1(1, 2, SM, SC, SP);\
    EMIT1(2, 0, SM, SC, SP); EMIT1(2, 1, SM, SC, SP); EMIT1(2, 2, SM, SC, SP);\
} while (0)

    // batch loop: concentrates the live working set to ~75 MB (one batch)
    // so L3 evictions fall on dead lines. Not unrolled (I-cache).
    #pragma unroll 1
    for (int b = 0; b < NB; ++b) {
        const float* sb0 = pred + (size_t)b * ND * PLI + 3 * lane;
        const float* sb1 = targ + (size_t)b * ND * PLI + 3 * lane;

        // 18 phases k=0..17: plane d0-1+k -> slot k%3; EMIT from k>=2.
        TPM(0, d0 - 1);                       // k=0 (OOB only for first block)
        TPP(1, d0);                           // k=1
        #pragma unroll 1
        for (int gg = 0; gg < 5; ++gg) {      // k=2..16
            const int p = d0 + 1 + 3 * gg;
            TPP(2, p);     EMIT(0, 1, 2);
            TPP(0, p + 1); EMIT(1, 2, 0);
            TPP(1, p + 2); EMIT(2, 0, 1);
        }
        TPM(2, d0 + 16); EMIT(0, 1, 2);       // k=17 (OOB only for last block)
    }

#undef QROW
#undef TPASS
#undef TPP
#undef TPM
#undef EDGE1
#undef EMIT1
#undef EMIT

    // wave reduce -> block reduce -> one atomic per block
    #pragma unroll
    for (int off = 32; off > 0; off >>= 1)
        acc += __shfl_down(acc, off, 64);
    __shared__ float wsum[4];
    if (lane == 0) wsum[wid] = acc;
    __syncthreads();
    if (threadIdx.x == 0) {
        // fold the exact 1/16 kernel scale and the mean into one constant
        const float invN = 1.f / (16.f * (float)((long long)NB * ND * NH * NW));
        atomicAdd(out, (wsum[0] + wsum[1] + wsum[2] + wsum[3]) * invN);
    }
}

} // namespace

extern "C" void kernel_launch(void* const* d_in, const int* in_sizes, int n_in,
                              void* d_out, int out_size, void* d_ws, size_t ws_size,
                              hipStream_t stream) {
    const float* pred = (const float*)d_in[0];
    const float* targ = (const float*)d_in[1];
    float* out = (float*)d_out;
    (void)in_sizes; (void)n_in; (void)out_size; (void)d_ws; (void)ws_size;

    hipMemsetAsync(out, 0, sizeof(float), stream);

    dim3 grid(ND / CD, NH / 12, 1);   // (8, 16, 1) = 512 blocks, b-loop inside
    dim3 block(256);
    edge_loss3d<<<grid, block, 0, stream>>>(pred, targ, out);
}

// Round 21
// 41.361 us; speedup vs baseline: 2.6203x; 2.6203x over previous
//
#include <hip/hip_runtime.h>

namespace {

struct f3 { float x, y, z; };   // size 12, align 4 -> global_load_dwordx3

constexpr int NB = 4, ND = 128, NH = 192, NW = 192;
constexpr int PLI = NH * NW;
constexpr int CD = 16;    // output planes per block; 128/16 = 8 exact

__global__ __launch_bounds__(256, 2)
void edge_loss3d(const float* __restrict__ pred,
                 const float* __restrict__ targ,
                 float* __restrict__ out)
{
    const int lane = threadIdx.x & 63;
    const int wid  = threadIdx.x >> 6;
    const int d0   = blockIdx.x * CD;
    const int h    = blockIdx.y * 8 + 2 * wid; // wave's output rows h, h+1
    const int b    = blockIdx.z;

    // per-lane bases: 3 w-elements per lane, all 64 lanes active
    const float* sb0 = pred + (size_t)b * ND * PLI + 3 * lane;
    const float* sb1 = targ + (size_t)b * ND * PLI + 3 * lane;

    // 4 input rows h-1..h+2 (clamped) + wave-uniform edge masks
    const int ro0 = (h - 1 < 0 ? 0 : h - 1) * NW;
    const int ro1 = h * NW;
    const int ro2 = (h + 1) * NW;                      // always valid
    const int ro3 = (h + 2 > NH - 1 ? NH - 1 : h + 2) * NW;
    const float m0 = (h - 1 >= 0) ? 1.f : 0.f;
    const float m3 = (h + 2 < NH) ? 1.f : 0.f;

    // rolling UNSCALED conv state + TWO in-flight load sets (T14 ILP split)
    float q[2][3][3][2][3];
    f3 gA00, gA01, gA02, gA03, gA10, gA11, gA12, gA13;  // set A [tensor][row]
    f3 gB00, gB01, gB02, gB03, gB10, gB11, gB12, gB13;  // set B
    float acc = 0.f;

// issue the next plane's 8 dwordx3 loads into set S (no use until next phase)
#define PRE(S, OFS) do {                                                      \
    g##S##00 = *(const f3*)(sb0 + (OFS) + ro0);                               \
    g##S##01 = *(const f3*)(sb0 + (OFS) + ro1);                               \
    g##S##02 = *(const f3*)(sb0 + (OFS) + ro2);                               \
    g##S##03 = *(const f3*)(sb0 + (OFS) + ro3);                               \
    g##S##10 = *(const f3*)(sb1 + (OFS) + ro0);                               \
    g##S##11 = *(const f3*)(sb1 + (OFS) + ro1);                               \
    g##S##12 = *(const f3*)(sb1 + (OFS) + ro2);                               \
    g##S##13 = *(const f3*)(sb1 + (OFS) + ro3);                               \
} while (0)

// write one output row's (ss,ts,st) from named u/v + halos (literal indices)
#define QROW(T, SP, R, U0, U1, U2, UM, UP, V0, V1, V2, VM, VP) do {           \
    q[T][SP][0][R][0] = fmaf(2.f, U0, UM + U1);                               \
    q[T][SP][0][R][1] = fmaf(2.f, U1, U0 + U2);                               \
    q[T][SP][0][R][2] = fmaf(2.f, U2, U1 + UP);                               \
    q[T][SP][1][R][0] = fmaf(2.f, V0, VM + V1);                               \
    q[T][SP][1][R][1] = fmaf(2.f, V1, V0 + V2);                               \
    q[T][SP][1][R][2] = fmaf(2.f, V2, V1 + VP);                               \
    q[T][SP][2][R][0] = U1 - UM;                                              \
    q[T][SP][2][R][1] = U2 - U0;                                              \
    q[T][SP][2][R][2] = UP - U1;                                              \
} while (0)

// compute one tensor T of set S into slot SP (loads were issued last phase)
#define CMP1(S, T, SP, PM) do {                                               \
    const f3 A_ = g##S##T##0;                                                 \
    const f3 B_ = g##S##T##1;                                                 \
    const f3 C_ = g##S##T##2;                                                 \
    const f3 D_ = g##S##T##3;                                                 \
    const float a0_ = A_.x * m0, a1_ = A_.y * m0, a2_ = A_.z * m0;            \
    const float d0_ = D_.x * m3, d1_ = D_.y * m3, d2_ = D_.z * m3;            \
    float uA0_ = fmaf(2.f, B_.x, a0_ + C_.x) * (PM);                          \
    float uA1_ = fmaf(2.f, B_.y, a1_ + C_.y) * (PM);                          \
    float uA2_ = fmaf(2.f, B_.z, a2_ + C_.z) * (PM);                          \
    float uB0_ = fmaf(2.f, C_.x, B_.x + d0_) * (PM);                          \
    float uB1_ = fmaf(2.f, C_.y, B_.y + d1_) * (PM);                          \
    float uB2_ = fmaf(2.f, C_.z, B_.z + d2_) * (PM);                          \
    float vA0_ = (C_.x - a0_) * (PM), vA1_ = (C_.y - a1_) * (PM), vA2_ = (C_.z - a2_) * (PM); \
    float vB0_ = (d0_ - B_.x) * (PM), vB1_ = (d1_ - B_.y) * (PM), vB2_ = (d2_ - B_.z) * (PM); \
    float uAm_ = __shfl_up(uA2_, 1, 64), uAp_ = __shfl_down(uA0_, 1, 64);     \
    float uBm_ = __shfl_up(uB2_, 1, 64), uBp_ = __shfl_down(uB0_, 1, 64);     \
    float vAm_ = __shfl_up(vA2_, 1, 64), vAp_ = __shfl_down(vA0_, 1, 64);     \
    float vBm_ = __shfl_up(vB2_, 1, 64), vBp_ = __shfl_down(vB0_, 1, 64);     \
    if (lane == 0)  { uAm_ = 0.f; uBm_ = 0.f; vAm_ = 0.f; vBm_ = 0.f; }       \
    if (lane == 63) { uAp_ = 0.f; uBp_ = 0.f; vAp_ = 0.f; vBp_ = 0.f; }       \
    QROW(T, SP, 0, uA0_, uA1_, uA2_, uAm_, uAp_, vA0_, vA1_, vA2_, vAm_, vAp_); \
    QROW(T, SP, 1, uB0_, uB1_, uB2_, uBm_, uBp_, vB0_, vB1_, vB2_, vBm_, vBp_); \
} while (0)

#define CMP(S, SP, PM) do { CMP1(S, 0, SP, PM); CMP1(S, 1, SP, PM); } while (0)

// unscaled magnitude: conv scales exactly 16x; eps_u = 256e-8; v_sqrt 1 inst
#define EDGE1(T, R, J, SM, SC, SP, E) do {                                    \
    const float gx_ = fmaf(2.f, q[T][SC][2][R][J], q[T][SM][2][R][J] + q[T][SP][2][R][J]); \
    const float gy_ = fmaf(2.f, q[T][SC][1][R][J], q[T][SM][1][R][J] + q[T][SP][1][R][J]); \
    const float gz_ = q[T][SP][0][R][J] - q[T][SM][0][R][J];                  \
    const float d_ = fmaf(gz_, gz_, fmaf(gy_, gy_, fmaf(gx_, gx_, 2.56e-6f)));\
    asm("v_sqrt_f32 %0, %1" : "=v"(E) : "v"(d_));                             \
} while (0)

#define EMIT1(R, J, SM, SC, SP) do {                                          \
    float e0_, e1_;                                                           \
    EDGE1(0, R, J, SM, SC, SP, e0_);                                          \
    EDGE1(1, R, J, SM, SC, SP, e1_);                                          \
    acc += fabsf(e0_ - e1_);                                                  \
} while (0)

#define EMIT(SM, SC, SP) do {                                                 \
    EMIT1(0, 0, SM, SC, SP); EMIT1(0, 1, SM, SC, SP); EMIT1(0, 2, SM, SC, SP);\
    EMIT1(1, 0, SM, SC, SP); EMIT1(1, 1, SM, SC, SP); EMIT1(1, 2, SM, SC, SP);\
} while (0)

    // edge-plane clamps/masks (wave-uniform)
    const int   oF  = ((d0 - 1) < 0 ? 0 : (d0 - 1)) * PLI;
    const float pmF = (d0 - 1 >= 0) ? 1.f : 0.f;
    const int   oL  = ((d0 + 16) > ND - 1 ? ND - 1 : (d0 + 16)) * PLI;
    const float pmL = (d0 + 16 < ND) ? 1.f : 0.f;

    // 18 phases k=0..17: compute plane d0-1+k (set k%2, slot k%3) while
    // the OTHER set's loads for plane d0+k are in flight. No barriers.
    PRE(A, oF);
    PRE(B, d0 * PLI);       CMP(A, 0, pmF);                    // k=0
    PRE(A, (d0 + 1) * PLI); CMP(B, 1, 1.f);                    // k=1
    for (int gg = 0; gg < 2; ++gg) {                           // k=2..13
        const int p = d0 + 1 + 6 * gg;
        PRE(B, (p + 1) * PLI); CMP(A, 2, 1.f); EMIT(0, 1, 2);
        PRE(A, (p + 2) * PLI); CMP(B, 0, 1.f); EMIT(1, 2, 0);
        PRE(B, (p + 3) * PLI); CMP(A, 1, 1.f); EMIT(2, 0, 1);
        PRE(A, (p + 4) * PLI); CMP(B, 2, 1.f); EMIT(0, 1, 2);
        PRE(B, (p + 5) * PLI); CMP(A, 0, 1.f); EMIT(1, 2, 0);
        PRE(A, (p + 6) * PLI); CMP(B, 1, 1.f); EMIT(2, 0, 1);
    }
    PRE(B, (d0 + 14) * PLI); CMP(A, 2, 1.f); EMIT(0, 1, 2);    // k=14
    PRE(A, (d0 + 15) * PLI); CMP(B, 0, 1.f); EMIT(1, 2, 0);    // k=15
    PRE(B, oL);              CMP(A, 1, 1.f); EMIT(2, 0, 1);    // k=16
    CMP(B, 2, pmL);          EMIT(0, 1, 2);                    // k=17

#undef PRE
#undef QROW
#undef CMP1
#undef CMP
#undef EDGE1
#undef EMIT1
#undef EMIT

    // wave reduce -> block reduce -> one atomic per block
    #pragma unroll
    for (int off = 32; off > 0; off >>= 1)
        acc += __shfl_down(acc, off, 64);
    __shared__ float wsum[4];
    if (lane == 0) wsum[wid] = acc;
    __syncthreads();
    if (threadIdx.x == 0) {
        // fold the exact 1/16 kernel scale and the mean into one constant
        const float invN = 1.f / (16.f * (float)((long long)NB * ND * NH * NW));
        atomicAdd(out, (wsum[0] + wsum[1] + wsum[2] + wsum[3]) * invN);
    }
}

} // namespace

extern "C" void kernel_launch(void* const* d_in, const int* in_sizes, int n_in,
                              void* d_out, int out_size, void* d_ws, size_t ws_size,
                              hipStream_t stream) {
    const float* pred = (const float*)d_in[0];
    const float* targ = (const float*)d_in[1];
    float* out = (float*)d_out;
    (void)in_sizes; (void)n_in; (void)out_size; (void)d_ws; (void)ws_size;

    hipMemsetAsync(out, 0, sizeof(float), stream);

    dim3 grid(ND / CD, NH / 8, NB);   // (8, 24, 4) = 768 blocks, 12 waves/CU
    dim3 block(256);
    edge_loss3d<<<grid, block, 0, stream>>>(pred, targ, out);
}